// Round 2
// baseline (696.748 us; speedup 1.0000x reference)
//
#include <hip/hip_runtime.h>

// Problem constants (fixed by the reference)
#define NN   50000
#define EE   800000
#define DD   64
#define HH   128
#define KIN  320          // 5 * 64
#define TILE_E 64
#define SP   328          // psi_in LDS row stride in bf16 elems (320 + 8 pad, 16B align)
#define SH   136          // h1 LDS row stride (128 + 8 pad)

typedef __bf16 bf16x8 __attribute__((ext_vector_type(8)));
typedef float  f32x4  __attribute__((ext_vector_type(4)));

__device__ __forceinline__ float bf2f(unsigned short b) {
  union { unsigned int u; float f; } v; v.u = ((unsigned int)b) << 16; return v.f;
}
__device__ __forceinline__ unsigned short f2bf(float f) {
  union { float f; unsigned int u; } v; v.f = f;
  unsigned int u = v.u + 0x7FFFu + ((v.u >> 16) & 1u);   // round-to-nearest-even
  return (unsigned short)(u >> 16);
}
__device__ __forceinline__ unsigned int pk2(float a, float b) {
  return (unsigned int)f2bf(a) | ((unsigned int)f2bf(b) << 16);
}

// ---------------------------------------------------------------------------
// fp32 weights -> bf16, transposed to [n][k] so MFMA B-fragments are 16B runs.
// Total elements: 320*128 + 128*128 + 128*64 = 65536 -> exactly 256 blocks.
// ---------------------------------------------------------------------------
__global__ __launch_bounds__(256) void prep_weights(
    const float* __restrict__ W0,
    const float* __restrict__ W1,
    const float* __restrict__ W2,
    unsigned short* __restrict__ WT0,
    unsigned short* __restrict__ WT1,
    unsigned short* __restrict__ WT2) {
  int t = blockIdx.x * 256 + threadIdx.x;
  if (t < KIN * HH) {
    int k = t / HH, n = t % HH;
    WT0[n * KIN + k] = f2bf(W0[t]);
  } else if (t < KIN * HH + HH * HH) {
    int u = t - KIN * HH; int k = u / HH, n = u % HH;
    WT1[n * HH + k] = f2bf(W1[u]);
  } else {
    int u = t - KIN * HH - HH * HH; int k = u / DD, n = u % DD;
    WT2[n * HH + k] = f2bf(W2[u]);
  }
}

// ---------------------------------------------------------------------------
// Fused edge kernel: gather(fp32->bf16) -> 3-layer MLP (MFMA bf16, fp32 acc)
//                    -> s_ij -> fp32 atomic scatter into agg[N][64].
// Block: 256 threads (4 waves), 64 edges per block.
// Wave w owns hidden columns [32w, 32w+32); each weight matrix is read once
// per block (L2-resident).
// MFMA 16x16x32 bf16. A: m=lane&15, k=quad*8+j. B: n=lane&15, k=quad*8+j.
// C/D: col=lane&15, row=quad*4+reg.
// ---------------------------------------------------------------------------
__global__ __launch_bounds__(256) void edge_mlp(
    const float* __restrict__ hd,   // h_d_prev [N][64] fp32
    const float* __restrict__ hs,   // h_s      [N][64] fp32
    const float* __restrict__ ef,   // edge_feat[E][64] fp32
    const int* __restrict__ snd,
    const int* __restrict__ rcv,
    const unsigned short* __restrict__ WT0,  // [128][320] bf16
    const float* __restrict__ b0,            // [128] fp32
    const unsigned short* __restrict__ WT1,  // [128][128] bf16
    const float* __restrict__ b1,            // [128] fp32
    const unsigned short* __restrict__ WT2,  // [64][128] bf16
    const float* __restrict__ b2,            // [64] fp32
    float* __restrict__ agg)                 // [N][64] fp32
{
  // psi tile cols: [0:64)=h_si [64:128)=h_sj [128:192)=h_di [192:256)=h_dj [256:320)=ef
  // After layer0, cols [0:128) are dead -> reused as h2 storage.
  __shared__ __align__(16) unsigned short psi[TILE_E * SP];  // 41984 B
  __shared__ __align__(16) unsigned short h1[TILE_E * SH];   // 17408 B
  __shared__ int sidx[TILE_E];
  __shared__ int ridx[TILE_E];

  const int tid = threadIdx.x;
  const int e0  = blockIdx.x * TILE_E;

  if (tid < TILE_E)            sidx[tid] = snd[e0 + tid];
  else if (tid < 2 * TILE_E)   ridx[tid - TILE_E] = rcv[e0 + tid - TILE_E];
  __syncthreads();

  // Gather + fp32->bf16: 5 segs * 64 edges * 8 chunks(8 floats) = 2560 jobs.
  #pragma unroll
  for (int i = 0; i < 10; ++i) {
    int job = i * 256 + tid;
    int c   = job & 7;            // 8-float chunk within a 64-float row
    int e   = (job >> 3) & 63;    // edge within tile
    int seg = job >> 9;           // 0..4
    const float* src;
    if      (seg == 0) src = hs + (size_t)sidx[e] * DD;
    else if (seg == 1) src = hs + (size_t)ridx[e] * DD;
    else if (seg == 2) src = hd + (size_t)sidx[e] * DD;
    else if (seg == 3) src = hd + (size_t)ridx[e] * DD;
    else               src = ef + (size_t)(e0 + e) * DD;
    float4 v0 = *(const float4*)(src + c * 8);
    float4 v1 = *(const float4*)(src + c * 8 + 4);
    uint4 w;
    w.x = pk2(v0.x, v0.y); w.y = pk2(v0.z, v0.w);
    w.z = pk2(v1.x, v1.y); w.w = pk2(v1.z, v1.w);
    *(uint4*)(&psi[e * SP + seg * 64 + c * 8]) = w;
  }
  __syncthreads();

  const int wv   = tid >> 6;
  const int lane = tid & 63;
  const int ln   = lane & 15;
  const int quad = lane >> 4;

  // ------------------ Layer 0: [64,320] @ [320,128] -> h1 ------------------
  {
    f32x4 acc0[4], acc1[4];
    #pragma unroll
    for (int m = 0; m < 4; ++m) { acc0[m] = (f32x4){0,0,0,0}; acc1[m] = (f32x4){0,0,0,0}; }
    const unsigned short* wb0 = WT0 + (wv * 32 + ln) * KIN + quad * 8;
    const unsigned short* wb1 = wb0 + 16 * KIN;
    #pragma unroll
    for (int k0 = 0; k0 < 10; ++k0) {
      bf16x8 bf0 = *(const bf16x8*)(wb0 + k0 * 32);
      bf16x8 bf1 = *(const bf16x8*)(wb1 + k0 * 32);
      #pragma unroll
      for (int mt = 0; mt < 4; ++mt) {
        bf16x8 af = *(const bf16x8*)(&psi[(mt * 16 + ln) * SP + k0 * 32 + quad * 8]);
        acc0[mt] = __builtin_amdgcn_mfma_f32_16x16x32_bf16(af, bf0, acc0[mt], 0, 0, 0);
        acc1[mt] = __builtin_amdgcn_mfma_f32_16x16x32_bf16(af, bf1, acc1[mt], 0, 0, 0);
      }
    }
    float bv0 = b0[wv * 32 + ln];
    float bv1 = b0[wv * 32 + 16 + ln];
    #pragma unroll
    for (int mt = 0; mt < 4; ++mt) {
      #pragma unroll
      for (int i = 0; i < 4; ++i) {
        int row = mt * 16 + quad * 4 + i;
        float v0 = acc0[mt][i] + bv0; v0 = v0 > 0.f ? v0 : 0.f;
        float v1 = acc1[mt][i] + bv1; v1 = v1 > 0.f ? v1 : 0.f;
        h1[row * SH + wv * 32 + ln]      = f2bf(v0);
        h1[row * SH + wv * 32 + 16 + ln] = f2bf(v1);
      }
    }
  }
  __syncthreads();

  // ---------- Layer 1: [64,128] @ [128,128] -> h2 (aliases psi[:,0:128)) ----
  {
    f32x4 acc0[4], acc1[4];
    #pragma unroll
    for (int m = 0; m < 4; ++m) { acc0[m] = (f32x4){0,0,0,0}; acc1[m] = (f32x4){0,0,0,0}; }
    const unsigned short* wb0 = WT1 + (wv * 32 + ln) * HH + quad * 8;
    const unsigned short* wb1 = wb0 + 16 * HH;
    #pragma unroll
    for (int k0 = 0; k0 < 4; ++k0) {
      bf16x8 bf0 = *(const bf16x8*)(wb0 + k0 * 32);
      bf16x8 bf1 = *(const bf16x8*)(wb1 + k0 * 32);
      #pragma unroll
      for (int mt = 0; mt < 4; ++mt) {
        bf16x8 af = *(const bf16x8*)(&h1[(mt * 16 + ln) * SH + k0 * 32 + quad * 8]);
        acc0[mt] = __builtin_amdgcn_mfma_f32_16x16x32_bf16(af, bf0, acc0[mt], 0, 0, 0);
        acc1[mt] = __builtin_amdgcn_mfma_f32_16x16x32_bf16(af, bf1, acc1[mt], 0, 0, 0);
      }
    }
    float bv0 = b1[wv * 32 + ln];
    float bv1 = b1[wv * 32 + 16 + ln];
    #pragma unroll
    for (int mt = 0; mt < 4; ++mt) {
      #pragma unroll
      for (int i = 0; i < 4; ++i) {
        int row = mt * 16 + quad * 4 + i;
        float v0 = acc0[mt][i] + bv0; v0 = v0 > 0.f ? v0 : 0.f;
        float v1 = acc1[mt][i] + bv1; v1 = v1 > 0.f ? v1 : 0.f;
        psi[row * SP + wv * 32 + ln]      = f2bf(v0);   // h2 into dead cols
        psi[row * SP + wv * 32 + 16 + ln] = f2bf(v1);
      }
    }
  }
  __syncthreads();

  // ---------- Layer 2: [64,128] @ [128,64] -> psi, s_ij, atomic scatter ----
  {
    f32x4 acc[4];
    #pragma unroll
    for (int m = 0; m < 4; ++m) acc[m] = (f32x4){0,0,0,0};
    const unsigned short* wb = WT2 + (wv * 16 + ln) * HH + quad * 8;
    #pragma unroll
    for (int k0 = 0; k0 < 4; ++k0) {
      bf16x8 bf = *(const bf16x8*)(wb + k0 * 32);
      #pragma unroll
      for (int mt = 0; mt < 4; ++mt) {
        bf16x8 af = *(const bf16x8*)(&psi[(mt * 16 + ln) * SP + k0 * 32 + quad * 8]);
        acc[mt] = __builtin_amdgcn_mfma_f32_16x16x32_bf16(af, bf, acc[mt], 0, 0, 0);
      }
    }
    int   col = wv * 16 + ln;   // waves 0..3 cover cols 0..63 (wv*16+ln, ln<16)
    float bv  = b2[col];
    #pragma unroll
    for (int mt = 0; mt < 4; ++mt) {
      #pragma unroll
      for (int i = 0; i < 4; ++i) {
        int row = mt * 16 + quad * 4 + i;
        float p = acc[mt][i] + bv; p = p > 0.f ? p : 0.f;
        float di = bf2f(psi[row * SP + 128 + col]);
        float dj = bf2f(psi[row * SP + 192 + col]);
        float s  = p * (dj - di);
        atomicAdd(&agg[(size_t)ridx[row] * DD + col], s);
      }
    }
  }
}

// ---------------------------------------------------------------------------
// out = h_d_prev + agg @ Wm   (all fp32)   [50000,64]; 4 rows per block.
// ---------------------------------------------------------------------------
__global__ __launch_bounds__(256) void final_out(
    const float* __restrict__ hd,
    const float* __restrict__ agg,
    const float* __restrict__ Wm,   // [64][64] fp32
    float* __restrict__ out)
{
  __shared__ float wmf[DD * DD];    // 16 KB
  int tid = threadIdx.x;
  #pragma unroll
  for (int i = tid; i < DD * DD; i += 256) wmf[i] = Wm[i];
  __syncthreads();

  int row = blockIdx.x * 4 + (tid >> 6);
  int c   = tid & 63;
  const float* ar = agg + (size_t)row * DD;
  float s = 0.f;
  #pragma unroll
  for (int k = 0; k < DD; ++k) s += ar[k] * wmf[k * DD + c];   // ar[k]: wave-broadcast
  size_t o = (size_t)row * DD + c;
  out[o] = hd[o] + s;
}

// ---------------------------------------------------------------------------
extern "C" void kernel_launch(void* const* d_in, const int* in_sizes, int n_in,
                              void* d_out, int out_size, void* d_ws, size_t ws_size,
                              hipStream_t stream) {
  const float* hd = (const float*)d_in[0];
  const float* hs = (const float*)d_in[1];
  const float* ef = (const float*)d_in[2];
  const int* snd  = (const int*)d_in[3];
  const int* rcv  = (const int*)d_in[4];
  const float* W0 = (const float*)d_in[5];
  const float* b0 = (const float*)d_in[6];
  const float* W1 = (const float*)d_in[7];
  const float* b1 = (const float*)d_in[8];
  const float* W2 = (const float*)d_in[9];
  const float* b2 = (const float*)d_in[10];
  const float* Wm = (const float*)d_in[11];
  float* out      = (float*)d_out;

  char* ws = (char*)d_ws;
  float* agg = (float*)ws;                                   // 50000*64*4 = 12.8 MB
  unsigned short* WT0 = (unsigned short*)(ws + 12800000);    // 320*128*2
  unsigned short* WT1 = WT0 + KIN * HH;                      // 128*128*2
  unsigned short* WT2 = WT1 + HH * HH;                       // 64*128*2

  hipMemsetAsync(agg, 0, (size_t)NN * DD * sizeof(float), stream);
  prep_weights<<<256, 256, 0, stream>>>(W0, W1, W2, WT0, WT1, WT2);
  edge_mlp<<<EE / TILE_E, 256, 0, stream>>>(hd, hs, ef, snd, rcv,
                                            WT0, b0, WT1, b1, WT2, b2, agg);
  final_out<<<NN / 4, 256, 0, stream>>>(hd, agg, Wm, out);
}

// Round 4
// 587.021 us; speedup vs baseline: 1.1869x; 1.1869x over previous
//
#include <hip/hip_runtime.h>

// Problem constants (fixed by the reference)
#define NN   50000
#define EE   800000
#define DD   64
#define HH   128
#define KIN  320          // 5 * 64
#define TILE_E 64

typedef __bf16 bf16x8 __attribute__((ext_vector_type(8)));
typedef float  f32x4  __attribute__((ext_vector_type(4)));

#if __has_builtin(__builtin_amdgcn_cvt_pk_bf16_f32)
typedef __bf16 bf16x2_t __attribute__((ext_vector_type(2)));
__device__ __forceinline__ unsigned int pk2(float a, float b) {
  union { bf16x2_t v; unsigned int u; } cv;
  cv.v = __builtin_amdgcn_cvt_pk_bf16_f32(a, b);
  return cv.u;
}
__device__ __forceinline__ unsigned short f2bf(float a) {
  return (unsigned short)(pk2(a, a) & 0xFFFFu);
}
#else
__device__ __forceinline__ unsigned short f2bf(float f) {
  union { float f; unsigned int u; } v; v.f = f;
  unsigned int u = v.u + 0x7FFFu + ((v.u >> 16) & 1u);   // RTNE
  return (unsigned short)(u >> 16);
}
__device__ __forceinline__ unsigned int pk2(float a, float b) {
  return (unsigned int)f2bf(a) | ((unsigned int)f2bf(b) << 16);
}
#endif

__device__ __forceinline__ float bf2f(unsigned short b) {
  union { unsigned int u; float f; } v; v.u = ((unsigned int)b) << 16; return v.f;
}

// Packed, pad-free psi layout in 16B units: unit = (mt*10 + k0)*64 + row15*4 + quad
// where mt=row>>4, row15=row&15, k0=kk>>5, quad=(kk>>3)&3, elem=kk&7.
// u16 index for (row in [0,64), kk in [0,320)):
__device__ __forceinline__ int psiIdx(int row, int kk) {
  return ((((row >> 4) * 10 + (kk >> 5)) << 6) + ((row & 15) << 2) + ((kk >> 3) & 3)) * 8
         + (kk & 7);
}

// ---------------------------------------------------------------------------
// fp32 weights -> bf16, transposed to [n][k] so MFMA B-fragments are 16B runs.
// Total elements: 320*128 + 128*128 + 128*64 = 65536 -> exactly 256 blocks.
// ---------------------------------------------------------------------------
__global__ __launch_bounds__(256) void prep_weights(
    const float* __restrict__ W0,
    const float* __restrict__ W1,
    const float* __restrict__ W2,
    unsigned short* __restrict__ WT0,
    unsigned short* __restrict__ WT1,
    unsigned short* __restrict__ WT2) {
  int t = blockIdx.x * 256 + threadIdx.x;
  if (t < KIN * HH) {
    int k = t / HH, n = t % HH;
    WT0[n * KIN + k] = f2bf(W0[t]);
  } else if (t < KIN * HH + HH * HH) {
    int u = t - KIN * HH; int k = u / HH, n = u % HH;
    WT1[n * HH + k] = f2bf(W1[u]);
  } else {
    int u = t - KIN * HH - HH * HH; int k = u / DD, n = u % DD;
    WT2[n * HH + k] = f2bf(W2[u]);
  }
}

// ---------------------------------------------------------------------------
// Fused edge kernel. 256 threads (4 waves), 64 edges/block, LDS = 40960 B
// exactly -> 4 blocks/CU. Layer outputs are register-staged and overwrite the
// dead h_si|h_sj region (kk [0,128)) as h1, then h2. di/dj (kk [128,256))
// survive to the epilogue.
// MFMA 16x16x32 bf16. A: m=lane&15, k=quad*8+j. B: n=lane&15, k=quad*8+j.
// C/D: col=lane&15, row=quad*4+reg.
// ---------------------------------------------------------------------------
__global__ __launch_bounds__(256, 4) void edge_mlp(
    const float* __restrict__ hd,   // h_d_prev [N][64] fp32
    const float* __restrict__ hs,   // h_s      [N][64] fp32
    const float* __restrict__ ef,   // edge_feat[E][64] fp32
    const int* __restrict__ snd,
    const int* __restrict__ rcv,
    const unsigned short* __restrict__ WT0,  // [128][320] bf16
    const float* __restrict__ b0,            // [128]
    const unsigned short* __restrict__ WT1,  // [128][128] bf16
    const float* __restrict__ b1,            // [128]
    const unsigned short* __restrict__ WT2,  // [64][128] bf16
    const float* __restrict__ b2,            // [64]
    float* __restrict__ agg)                 // [N][64] fp32
{
  __shared__ __align__(16) unsigned short psi[TILE_E * KIN];  // 40960 B exactly

  const int tid  = threadIdx.x;
  const int e0   = blockIdx.x * TILE_E;
  const int wv   = tid >> 6;
  const int lane = tid & 63;
  const int ln   = lane & 15;
  const int quad = lane >> 4;

  // Preload the 16 receiver indices this lane scatters to (hidden by gather).
  int ridx[16];
  #pragma unroll
  for (int mt = 0; mt < 4; ++mt)
    #pragma unroll
    for (int i = 0; i < 4; ++i)
      ridx[mt * 4 + i] = rcv[e0 + mt * 16 + quad * 4 + i];

  // Gather + fp32->bf16. seg = i>>1 is a compile-time constant per iteration.
  #pragma unroll
  for (int i = 0; i < 10; ++i) {
    const int seg = i >> 1;                    // 0..4
    int e = ((i << 5) + (tid >> 3)) & 63;      // edge within tile
    int c = tid & 7;                           // 8-float chunk of the row
    const float* src;
    if      (seg == 0) src = hs + (size_t)snd[e0 + e] * DD;
    else if (seg == 1) src = hs + (size_t)rcv[e0 + e] * DD;
    else if (seg == 2) src = hd + (size_t)snd[e0 + e] * DD;
    else if (seg == 3) src = hd + (size_t)rcv[e0 + e] * DD;
    else               src = ef + (size_t)(e0 + e) * DD;
    float4 v0 = *(const float4*)(src + c * 8);
    float4 v1 = *(const float4*)(src + c * 8 + 4);
    uint4 w;
    w.x = pk2(v0.x, v0.y); w.y = pk2(v0.z, v0.w);
    w.z = pk2(v1.x, v1.y); w.w = pk2(v1.z, v1.w);
    int unit = (((e >> 4) * 10 + seg * 2 + (c >> 2)) << 6) + ((e & 15) << 2) + (c & 3);
    *(uint4*)(&psi[unit * 8]) = w;
  }
  __syncthreads();

  f32x4 acc0[4], acc1[4];

  // ------------------ Layer 0: [64,320] @ [320,128] ------------------------
  {
    #pragma unroll
    for (int m = 0; m < 4; ++m) { acc0[m] = (f32x4){0,0,0,0}; acc1[m] = (f32x4){0,0,0,0}; }
    const unsigned short* wb0 = WT0 + (wv * 32 + ln) * KIN + quad * 8;
    const unsigned short* wb1 = wb0 + 16 * KIN;
    #pragma unroll
    for (int k0 = 0; k0 < 10; ++k0) {
      bf16x8 bf0 = *(const bf16x8*)(wb0 + k0 * 32);
      bf16x8 bf1 = *(const bf16x8*)(wb1 + k0 * 32);
      #pragma unroll
      for (int mt = 0; mt < 4; ++mt) {
        bf16x8 af = *(const bf16x8*)(&psi[(((mt * 10 + k0) << 6) + (ln << 2) + quad) * 8]);
        acc0[mt] = __builtin_amdgcn_mfma_f32_16x16x32_bf16(af, bf0, acc0[mt], 0, 0, 0);
        acc1[mt] = __builtin_amdgcn_mfma_f32_16x16x32_bf16(af, bf1, acc1[mt], 0, 0, 0);
      }
    }
  }
  __syncthreads();          // psi input reads done -> safe to overwrite kk[0,128)

  // h1 -> kk [0,128): element (row, n=wv*32+ln(+16))
  {
    float bv0 = b0[wv * 32 + ln];
    float bv1 = b0[wv * 32 + 16 + ln];
    #pragma unroll
    for (int mt = 0; mt < 4; ++mt) {
      #pragma unroll
      for (int i = 0; i < 4; ++i) {
        int base = ((mt * 10 + wv) << 6) + ((quad * 4 + i) << 2) + (ln >> 3);
        float v0 = acc0[mt][i] + bv0; v0 = v0 > 0.f ? v0 : 0.f;
        float v1 = acc1[mt][i] + bv1; v1 = v1 > 0.f ? v1 : 0.f;
        psi[base * 8 + (ln & 7)]       = f2bf(v0);
        psi[(base + 2) * 8 + (ln & 7)] = f2bf(v1);
      }
    }
  }
  __syncthreads();

  // ------------------ Layer 1: [64,128] @ [128,128] ------------------------
  {
    #pragma unroll
    for (int m = 0; m < 4; ++m) { acc0[m] = (f32x4){0,0,0,0}; acc1[m] = (f32x4){0,0,0,0}; }
    const unsigned short* wb0 = WT1 + (wv * 32 + ln) * HH + quad * 8;
    const unsigned short* wb1 = wb0 + 16 * HH;
    #pragma unroll
    for (int k0 = 0; k0 < 4; ++k0) {
      bf16x8 bf0 = *(const bf16x8*)(wb0 + k0 * 32);
      bf16x8 bf1 = *(const bf16x8*)(wb1 + k0 * 32);
      #pragma unroll
      for (int mt = 0; mt < 4; ++mt) {
        bf16x8 af = *(const bf16x8*)(&psi[(((mt * 10 + k0) << 6) + (ln << 2) + quad) * 8]);
        acc0[mt] = __builtin_amdgcn_mfma_f32_16x16x32_bf16(af, bf0, acc0[mt], 0, 0, 0);
        acc1[mt] = __builtin_amdgcn_mfma_f32_16x16x32_bf16(af, bf1, acc1[mt], 0, 0, 0);
      }
    }
  }
  __syncthreads();          // h1 reads done -> overwrite with h2

  {
    float bv0 = b1[wv * 32 + ln];
    float bv1 = b1[wv * 32 + 16 + ln];
    #pragma unroll
    for (int mt = 0; mt < 4; ++mt) {
      #pragma unroll
      for (int i = 0; i < 4; ++i) {
        int base = ((mt * 10 + wv) << 6) + ((quad * 4 + i) << 2) + (ln >> 3);
        float v0 = acc0[mt][i] + bv0; v0 = v0 > 0.f ? v0 : 0.f;
        float v1 = acc1[mt][i] + bv1; v1 = v1 > 0.f ? v1 : 0.f;
        psi[base * 8 + (ln & 7)]       = f2bf(v0);
        psi[(base + 2) * 8 + (ln & 7)] = f2bf(v1);
      }
    }
  }
  __syncthreads();

  // ---------- Layer 2: [64,128] @ [128,64] + s_ij + atomic scatter ---------
  {
    f32x4 acc[4];
    #pragma unroll
    for (int m = 0; m < 4; ++m) acc[m] = (f32x4){0,0,0,0};
    const unsigned short* wb = WT2 + (wv * 16 + ln) * HH + quad * 8;
    #pragma unroll
    for (int k0 = 0; k0 < 4; ++k0) {
      bf16x8 bf = *(const bf16x8*)(wb + k0 * 32);
      #pragma unroll
      for (int mt = 0; mt < 4; ++mt) {
        bf16x8 af = *(const bf16x8*)(&psi[(((mt * 10 + k0) << 6) + (ln << 2) + quad) * 8]);
        acc[mt] = __builtin_amdgcn_mfma_f32_16x16x32_bf16(af, bf, acc[mt], 0, 0, 0);
      }
    }
    int   col = wv * 16 + ln;   // waves 0..3 cover cols 0..63
    float bv  = b2[col];
    #pragma unroll
    for (int mt = 0; mt < 4; ++mt) {
      #pragma unroll
      for (int i = 0; i < 4; ++i) {
        int row = mt * 16 + quad * 4 + i;
        float p  = acc[mt][i] + bv; p = p > 0.f ? p : 0.f;
        float di = bf2f(psi[psiIdx(row, 128 + col)]);
        float dj = bf2f(psi[psiIdx(row, 192 + col)]);
        float s  = p * (dj - di);
        atomicAdd(&agg[(size_t)ridx[mt * 4 + i] * DD + col], s);
      }
    }
  }
}

// ---------------------------------------------------------------------------
// out = h_d_prev + agg @ Wm   (all fp32)   [50000,64]; 4 rows per block.
// ---------------------------------------------------------------------------
__global__ __launch_bounds__(256) void final_out(
    const float* __restrict__ hd,
    const float* __restrict__ agg,
    const float* __restrict__ Wm,   // [64][64] fp32
    float* __restrict__ out)
{
  __shared__ float wmf[DD * DD];    // 16 KB
  int tid = threadIdx.x;
  #pragma unroll
  for (int i = tid; i < DD * DD; i += 256) wmf[i] = Wm[i];
  __syncthreads();

  int row = blockIdx.x * 4 + (tid >> 6);
  int c   = tid & 63;
  const float* ar = agg + (size_t)row * DD;   // wave-uniform -> s_load
  float s = 0.f;
  #pragma unroll
  for (int k = 0; k < DD; ++k) s += ar[k] * wmf[k * DD + c];
  size_t o = (size_t)row * DD + c;
  out[o] = hd[o] + s;
}

// ---------------------------------------------------------------------------
extern "C" void kernel_launch(void* const* d_in, const int* in_sizes, int n_in,
                              void* d_out, int out_size, void* d_ws, size_t ws_size,
                              hipStream_t stream) {
  const float* hd = (const float*)d_in[0];
  const float* hs = (const float*)d_in[1];
  const float* ef = (const float*)d_in[2];
  const int* snd  = (const int*)d_in[3];
  const int* rcv  = (const int*)d_in[4];
  const float* W0 = (const float*)d_in[5];
  const float* b0 = (const float*)d_in[6];
  const float* W1 = (const float*)d_in[7];
  const float* b1 = (const float*)d_in[8];
  const float* W2 = (const float*)d_in[9];
  const float* b2 = (const float*)d_in[10];
  const float* Wm = (const float*)d_in[11];
  float* out      = (float*)d_out;

  char* ws = (char*)d_ws;
  float* agg = (float*)ws;                                   // 50000*64*4 = 12.8 MB
  unsigned short* WT0 = (unsigned short*)(ws + 12800000);    // 320*128*2
  unsigned short* WT1 = WT0 + KIN * HH;                      // 128*128*2
  unsigned short* WT2 = WT1 + HH * HH;                       // 64*128*2

  hipMemsetAsync(agg, 0, (size_t)NN * DD * sizeof(float), stream);
  prep_weights<<<256, 256, 0, stream>>>(W0, W1, W2, WT0, WT1, WT2);
  edge_mlp<<<EE / TILE_E, 256, 0, stream>>>(hd, hs, ef, snd, rcv,
                                            WT0, b0, WT1, b1, WT2, b2, agg);
  final_out<<<NN / 4, 256, 0, stream>>>(hd, agg, Wm, out);
}

// Round 6
// 536.819 us; speedup vs baseline: 1.2979x; 1.0935x over previous
//
#include <hip/hip_runtime.h>

// Problem constants (fixed by the reference)
#define NN   50000
#define EE   800000
#define DD   64
#define HH   128
#define KIN  320          // 5 * 64
#define TILE_E 64

typedef __bf16 bf16x8 __attribute__((ext_vector_type(8)));
typedef float  f32x4  __attribute__((ext_vector_type(4)));

#if __has_builtin(__builtin_amdgcn_cvt_pk_bf16_f32)
typedef __bf16 bf16x2_t __attribute__((ext_vector_type(2)));
__device__ __forceinline__ unsigned int pk2(float a, float b) {
  union { bf16x2_t v; unsigned int u; } cv;
  cv.v = __builtin_amdgcn_cvt_pk_bf16_f32(a, b);
  return cv.u;
}
__device__ __forceinline__ unsigned short f2bf(float a) {
  return (unsigned short)(pk2(a, a) & 0xFFFFu);
}
#else
__device__ __forceinline__ unsigned short f2bf(float f) {
  union { float f; unsigned int u; } v; v.f = f;
  unsigned int u = v.u + 0x7FFFu + ((v.u >> 16) & 1u);   // RTNE
  return (unsigned short)(u >> 16);
}
__device__ __forceinline__ unsigned int pk2(float a, float b) {
  return (unsigned int)f2bf(a) | ((unsigned int)f2bf(b) << 16);
}
#endif

__device__ __forceinline__ float bf2f(unsigned short b) {
  union { unsigned int u; float f; } v; v.u = ((unsigned int)b) << 16; return v.f;
}

// Packed, pad-free psi layout in 16B units: unit = (mt*10 + k0)*64 + row15*4 + quad
// u16 index for (row in [0,64), kk in [0,320)):
__device__ __forceinline__ int psiIdx(int row, int kk) {
  return ((((row >> 4) * 10 + (kk >> 5)) << 6) + ((row & 15) << 2) + ((kk >> 3) & 3)) * 8
         + (kk & 7);
}

// ---------------------------------------------------------------------------
// fp32 weights -> bf16, transposed to [n][k] so MFMA B-fragments are 16B runs.
// ---------------------------------------------------------------------------
__global__ __launch_bounds__(256) void prep_weights(
    const float* __restrict__ W0,
    const float* __restrict__ W1,
    const float* __restrict__ W2,
    unsigned short* __restrict__ WT0,
    unsigned short* __restrict__ WT1,
    unsigned short* __restrict__ WT2) {
  int t = blockIdx.x * 256 + threadIdx.x;
  if (t < KIN * HH) {
    int k = t / HH, n = t % HH;
    WT0[n * KIN + k] = f2bf(W0[t]);
  } else if (t < KIN * HH + HH * HH) {
    int u = t - KIN * HH; int k = u / HH, n = u % HH;
    WT1[n * HH + k] = f2bf(W1[u]);
  } else {
    int u = t - KIN * HH - HH * HH; int k = u / DD, n = u % DD;
    WT2[n * HH + k] = f2bf(W2[u]);
  }
}

// ---------------------------------------------------------------------------
// fp32 node tables -> bf16 tables (halves random-gather bytes in edge_mlp).
// 800000 jobs of 8 elements; grid 3125 x 256.
// ---------------------------------------------------------------------------
__global__ __launch_bounds__(256) void prep_tables(
    const float* __restrict__ hd, const float* __restrict__ hs,
    unsigned short* __restrict__ hdb, unsigned short* __restrict__ hsb) {
  int t = blockIdx.x * 256 + threadIdx.x;
  const int n = NN * DD / 8;              // 400000
  const float* src; unsigned short* dst; int i;
  if (t < n) { src = hd; dst = hdb; i = t; }
  else       { src = hs; dst = hsb; i = t - n; }
  float4 a = *(const float4*)(src + (size_t)i * 8);
  float4 b = *(const float4*)(src + (size_t)i * 8 + 4);
  uint4 w;
  w.x = pk2(a.x, a.y); w.y = pk2(a.z, a.w);
  w.z = pk2(b.x, b.y); w.w = pk2(b.z, b.w);
  *(uint4*)(dst + (size_t)i * 8) = w;
}

// ---------------------------------------------------------------------------
// Fused edge kernel. 256 threads (4 waves), 64 edges/block, LDS = 40960 B
// -> 4 blocks/CU. h1/h2 register-staged into the dead kk[0,128) region.
// Epilogue: scalar fp32 atomicAdd scatter (native global_atomic_add_f32).
// ---------------------------------------------------------------------------
__global__ __launch_bounds__(256, 4) void edge_mlp(
    const unsigned short* __restrict__ hdb,  // h_d_prev [N][64] bf16
    const unsigned short* __restrict__ hsb,  // h_s      [N][64] bf16
    const float* __restrict__ ef,            // edge_feat[E][64] fp32
    const int* __restrict__ snd,
    const int* __restrict__ rcv,
    const unsigned short* __restrict__ WT0,  // [128][320] bf16
    const float* __restrict__ b0,            // [128]
    const unsigned short* __restrict__ WT1,  // [128][128] bf16
    const float* __restrict__ b1,            // [128]
    const unsigned short* __restrict__ WT2,  // [64][128] bf16
    const float* __restrict__ b2,            // [64]
    float* __restrict__ agg)                 // [N][64] fp32
{
  __shared__ __align__(16) unsigned short psi[TILE_E * KIN];  // 40960 B exactly

  const int tid  = threadIdx.x;
  const int e0   = blockIdx.x * TILE_E;
  const int wv   = tid >> 6;
  const int lane = tid & 63;
  const int ln   = lane & 15;
  const int quad = lane >> 4;

  // Preload the 16 receiver indices this lane scatters to (hidden by gather).
  int ridx[16];
  #pragma unroll
  for (int mt = 0; mt < 4; ++mt)
    #pragma unroll
    for (int i = 0; i < 4; ++i)
      ridx[mt * 4 + i] = rcv[e0 + mt * 16 + quad * 4 + i];

  // Gather. segs 0-3: bf16 table rows (16B/job). seg 4: ef fp32, pack to bf16.
  #pragma unroll
  for (int i = 0; i < 10; ++i) {
    const int seg = i >> 1;                    // compile-time 0..4
    int e = ((i << 5) + (tid >> 3)) & 63;      // edge within tile
    int c = tid & 7;                           // 16B chunk of the row
    int unit = (((e >> 4) * 10 + seg * 2 + (c >> 2)) << 6) + ((e & 15) << 2) + (c & 3);
    uint4 w;
    if (seg < 4) {
      const unsigned short* tb = (seg & 2) ? hdb : hsb;   // 0,1=h_s  2,3=h_d
      const int* ix = (seg & 1) ? rcv : snd;
      w = *(const uint4*)(tb + (size_t)ix[e0 + e] * DD + c * 8);
    } else {
      const float* src = ef + (size_t)(e0 + e) * DD;
      float4 v0 = *(const float4*)(src + c * 8);
      float4 v1 = *(const float4*)(src + c * 8 + 4);
      w.x = pk2(v0.x, v0.y); w.y = pk2(v0.z, v0.w);
      w.z = pk2(v1.x, v1.y); w.w = pk2(v1.z, v1.w);
    }
    *(uint4*)(&psi[unit * 8]) = w;
  }
  __syncthreads();

  f32x4 acc0[4], acc1[4];

  // ------------------ Layer 0: [64,320] @ [320,128] ------------------------
  {
    #pragma unroll
    for (int m = 0; m < 4; ++m) { acc0[m] = (f32x4){0,0,0,0}; acc1[m] = (f32x4){0,0,0,0}; }
    const unsigned short* wb0 = WT0 + (wv * 32 + ln) * KIN + quad * 8;
    const unsigned short* wb1 = wb0 + 16 * KIN;
    #pragma unroll
    for (int k0 = 0; k0 < 10; ++k0) {
      bf16x8 bf0 = *(const bf16x8*)(wb0 + k0 * 32);
      bf16x8 bf1 = *(const bf16x8*)(wb1 + k0 * 32);
      #pragma unroll
      for (int mt = 0; mt < 4; ++mt) {
        bf16x8 af = *(const bf16x8*)(&psi[(((mt * 10 + k0) << 6) + (ln << 2) + quad) * 8]);
        acc0[mt] = __builtin_amdgcn_mfma_f32_16x16x32_bf16(af, bf0, acc0[mt], 0, 0, 0);
        acc1[mt] = __builtin_amdgcn_mfma_f32_16x16x32_bf16(af, bf1, acc1[mt], 0, 0, 0);
      }
    }
  }
  __syncthreads();          // psi input reads done -> safe to overwrite kk[0,128)

  // h1 -> kk [0,128)
  {
    float bv0 = b0[wv * 32 + ln];
    float bv1 = b0[wv * 32 + 16 + ln];
    #pragma unroll
    for (int mt = 0; mt < 4; ++mt) {
      #pragma unroll
      for (int i = 0; i < 4; ++i) {
        int base = ((mt * 10 + wv) << 6) + ((quad * 4 + i) << 2) + (ln >> 3);
        float v0 = acc0[mt][i] + bv0; v0 = v0 > 0.f ? v0 : 0.f;
        float v1 = acc1[mt][i] + bv1; v1 = v1 > 0.f ? v1 : 0.f;
        psi[base * 8 + (ln & 7)]       = f2bf(v0);
        psi[(base + 2) * 8 + (ln & 7)] = f2bf(v1);
      }
    }
  }
  __syncthreads();

  // ------------------ Layer 1: [64,128] @ [128,128] ------------------------
  {
    #pragma unroll
    for (int m = 0; m < 4; ++m) { acc0[m] = (f32x4){0,0,0,0}; acc1[m] = (f32x4){0,0,0,0}; }
    const unsigned short* wb0 = WT1 + (wv * 32 + ln) * HH + quad * 8;
    const unsigned short* wb1 = wb0 + 16 * HH;
    #pragma unroll
    for (int k0 = 0; k0 < 4; ++k0) {
      bf16x8 bf0 = *(const bf16x8*)(wb0 + k0 * 32);
      bf16x8 bf1 = *(const bf16x8*)(wb1 + k0 * 32);
      #pragma unroll
      for (int mt = 0; mt < 4; ++mt) {
        bf16x8 af = *(const bf16x8*)(&psi[(((mt * 10 + k0) << 6) + (ln << 2) + quad) * 8]);
        acc0[mt] = __builtin_amdgcn_mfma_f32_16x16x32_bf16(af, bf0, acc0[mt], 0, 0, 0);
        acc1[mt] = __builtin_amdgcn_mfma_f32_16x16x32_bf16(af, bf1, acc1[mt], 0, 0, 0);
      }
    }
  }
  __syncthreads();          // h1 reads done -> overwrite with h2

  {
    float bv0 = b1[wv * 32 + ln];
    float bv1 = b1[wv * 32 + 16 + ln];
    #pragma unroll
    for (int mt = 0; mt < 4; ++mt) {
      #pragma unroll
      for (int i = 0; i < 4; ++i) {
        int base = ((mt * 10 + wv) << 6) + ((quad * 4 + i) << 2) + (ln >> 3);
        float v0 = acc0[mt][i] + bv0; v0 = v0 > 0.f ? v0 : 0.f;
        float v1 = acc1[mt][i] + bv1; v1 = v1 > 0.f ? v1 : 0.f;
        psi[base * 8 + (ln & 7)]       = f2bf(v0);
        psi[(base + 2) * 8 + (ln & 7)] = f2bf(v1);
      }
    }
  }
  __syncthreads();

  // ---------- Layer 2: [64,128] @ [128,64] + s_ij + atomic scatter ---------
  {
    f32x4 acc[4];
    #pragma unroll
    for (int m = 0; m < 4; ++m) acc[m] = (f32x4){0,0,0,0};
    const unsigned short* wb = WT2 + (wv * 16 + ln) * HH + quad * 8;
    #pragma unroll
    for (int k0 = 0; k0 < 4; ++k0) {
      bf16x8 bf = *(const bf16x8*)(wb + k0 * 32);
      #pragma unroll
      for (int mt = 0; mt < 4; ++mt) {
        bf16x8 af = *(const bf16x8*)(&psi[(((mt * 10 + k0) << 6) + (ln << 2) + quad) * 8]);
        acc[mt] = __builtin_amdgcn_mfma_f32_16x16x32_bf16(af, bf, acc[mt], 0, 0, 0);
      }
    }
    int   col = wv * 16 + ln;   // waves 0..3 cover cols 0..63
    float bv  = b2[col];
    #pragma unroll
    for (int mt = 0; mt < 4; ++mt) {
      #pragma unroll
      for (int i = 0; i < 4; ++i) {
        int row = mt * 16 + quad * 4 + i;
        float p  = acc[mt][i] + bv; p = p > 0.f ? p : 0.f;
        float di = bf2f(psi[psiIdx(row, 128 + col)]);
        float dj = bf2f(psi[psiIdx(row, 192 + col)]);
        float s  = p * (dj - di);
        atomicAdd(&agg[(size_t)ridx[mt * 4 + i] * DD + col], s);
      }
    }
  }
}

// ---------------------------------------------------------------------------
// out = h_d_prev + agg @ Wm  (fp32). 16 rows/block, LDS-staged agg (stride 72
// swizzle: conflict-free broadcast) + float4 Wm reads. Grid 3125.
// ---------------------------------------------------------------------------
__global__ __launch_bounds__(256) void final_out(
    const float* __restrict__ hd,
    const float* __restrict__ agg,
    const float* __restrict__ Wm,   // [64][64] fp32
    float* __restrict__ out)
{
  __shared__ float wmf[DD * DD];    // 16 KB
  __shared__ float arow[16 * 72];   // 4.5 KB, stride-72 swizzle
  int tid = threadIdx.x;
  const float4* wm4 = (const float4*)Wm;
  float4* wf4 = (float4*)wmf;
  #pragma unroll
  for (int i = tid; i < DD * DD / 4; i += 256) wf4[i] = wm4[i];

  int r0 = blockIdx.x * 16;
  {
    float4 av = *(const float4*)(agg + (size_t)r0 * DD + tid * 4);
    int rr = tid >> 4, cc = (tid & 15) * 4;       // tid*4 == rr*64 + cc
    *(float4*)&arow[rr * 72 + cc] = av;
  }
  __syncthreads();

  int row = tid >> 4;
  int cq  = (tid & 15) * 4;
  f32x4 acc = (f32x4){0, 0, 0, 0};
  #pragma unroll
  for (int k = 0; k < DD; ++k) {
    float a = arow[row * 72 + k];
    f32x4 w = *(const f32x4*)&wmf[k * DD + cq];
    acc += a * w;
  }
  size_t o = ((size_t)(r0 + row)) * DD + cq;
  f32x4 h = *(const f32x4*)(hd + o);
  *(f32x4*)(out + o) = h + acc;
}

// ---------------------------------------------------------------------------
extern "C" void kernel_launch(void* const* d_in, const int* in_sizes, int n_in,
                              void* d_out, int out_size, void* d_ws, size_t ws_size,
                              hipStream_t stream) {
  const float* hd = (const float*)d_in[0];
  const float* hs = (const float*)d_in[1];
  const float* ef = (const float*)d_in[2];
  const int* snd  = (const int*)d_in[3];
  const int* rcv  = (const int*)d_in[4];
  const float* W0 = (const float*)d_in[5];
  const float* b0 = (const float*)d_in[6];
  const float* W1 = (const float*)d_in[7];
  const float* b1 = (const float*)d_in[8];
  const float* W2 = (const float*)d_in[9];
  const float* b2 = (const float*)d_in[10];
  const float* Wm = (const float*)d_in[11];
  float* out      = (float*)d_out;

  char* ws = (char*)d_ws;
  float* agg = (float*)ws;                                   // 12,800,000 B
  unsigned short* WT0 = (unsigned short*)(ws + 12800000);    // 81,920 B
  unsigned short* WT1 = WT0 + KIN * HH;                      // 32,768 B
  unsigned short* WT2 = WT1 + HH * HH;                       // 16,384 B
  unsigned short* hdb = WT2 + HH * DD;                       // 6,400,000 B
  unsigned short* hsb = hdb + (size_t)NN * DD;               // 6,400,000 B
                                                             // total ~25.8 MB
  hipMemsetAsync(agg, 0, (size_t)NN * DD * sizeof(float), stream);
  prep_weights<<<256, 256, 0, stream>>>(W0, W1, W2, WT0, WT1, WT2);
  prep_tables<<<NN * DD * 2 / 8 / 256, 256, 0, stream>>>(hd, hs, hdb, hsb);
  edge_mlp<<<EE / TILE_E, 256, 0, stream>>>(hdb, hsb, ef, snd, rcv,
                                            WT0, b0, WT1, b1, WT2, b2, agg);
  final_out<<<NN / 16, 256, 0, stream>>>(hd, agg, Wm, out);
}